// Round 5
// baseline (165.800 us; speedup 1.0000x reference)
//
#include <hip/hip_runtime.h>
#include <math.h>

#define BB 4
#define SS 256
#define DD 768
#define DEPC 100
#define HH 12

__device__ __forceinline__ float rdlane(float v, int l) {
    return __int_as_float(__builtin_amdgcn_readlane(__float_as_int(v), l));
}

// ---------- K1: u_t[h][p] = sum_d W_e[p][h*64+d] * w_rel[d]  (transposed) ----------
__global__ __launch_bounds__(256) void k_u(const float* __restrict__ W_e,
                                           const float* __restrict__ w_rel,
                                           float* __restrict__ u_t) {
    int e = blockIdx.x * 256 + threadIdx.x;
    if (e >= DEPC * HH) return;
    int p = e / HH, h = e % HH;
    const float4* we = (const float4*)(W_e + p * DD + h * 64);
    const float4* wr = (const float4*)w_rel;
    float acc = 0.f;
#pragma unroll
    for (int c = 0; c < 16; ++c) {
        float4 a = we[c], b = wr[c];
        acc += a.x * b.x + a.y * b.y + a.z * b.z + a.w * b.w;
    }
    u_t[h * DEPC + p] = acc;
}

// ---------- K2: V = token @ W_v  (1024x768 @ 768x768, fp32 tiled) ----------
#define TM 32
#define TN 64
#define TKK 16
__global__ __launch_bounds__(256) void k_v(const float* __restrict__ A,
                                           const float* __restrict__ Bm,
                                           float* __restrict__ C) {
    __shared__ float As[TKK][TM + 4];
    __shared__ float Bs[TKK][TN];
    int t = threadIdx.x;
    int tx = t & 15, ty = t >> 4;
    int r0 = blockIdx.x * TM, c0 = blockIdx.y * TN;
    float acc[2][4] = {};
    for (int k0 = 0; k0 < DD; k0 += TKK) {
        As[tx][ty]      = A[(r0 + ty) * DD + k0 + tx];
        As[tx][ty + 16] = A[(r0 + ty + 16) * DD + k0 + tx];
        int kb = t >> 6, cb = t & 63;
#pragma unroll
        for (int q = 0; q < 4; ++q)
            Bs[kb + 4 * q][cb] = Bm[(k0 + kb + 4 * q) * DD + c0 + cb];
        __syncthreads();
#pragma unroll
        for (int kk = 0; kk < TKK; ++kk) {
            float a0 = As[kk][2 * ty], a1 = As[kk][2 * ty + 1];
            float4 b = *(const float4*)&Bs[kk][4 * tx];
            acc[0][0] += a0 * b.x; acc[0][1] += a0 * b.y;
            acc[0][2] += a0 * b.z; acc[0][3] += a0 * b.w;
            acc[1][0] += a1 * b.x; acc[1][1] += a1 * b.y;
            acc[1][2] += a1 * b.z; acc[1][3] += a1 * b.w;
        }
        __syncthreads();
    }
#pragma unroll
    for (int m = 0; m < 2; ++m) {
        float4 v = make_float4(acc[m][0], acc[m][1], acc[m][2], acc[m][3]);
        *(float4*)&C[(size_t)(r0 + 2 * ty + m) * DD + c0 + 4 * tx] = v;
    }
}

// ---------- K3: fused scores + online-softmax + PV + relu(token+ctx) ----------
// Block = (i, b). 4 waves x 3 heads. Edge chunks double-buffered via global_load_lds;
// PV p-broadcast via v_readlane (VALU pipe), V reads coalesced from L2.
__global__ __launch_bounds__(256) void k_fused(const float* __restrict__ edge,
                                               const int* __restrict__ mask,
                                               const float* __restrict__ ut,
                                               const float* __restrict__ V,
                                               const float* __restrict__ token,
                                               float* __restrict__ out) {
    __shared__ float buf[2][64 * DEPC];  // 51.2 KB double-buffer
    int t = threadIdx.x;
    int i = blockIdx.x, b = blockIdx.y;
    int lane = t & 63, w = t >> 6;
    int hbase = __builtin_amdgcn_readfirstlane(w * 3);  // wave-uniform -> u via s_load
    const float* uw = ut + hbase * DEPC;
    const float* src = edge + (size_t)(b * SS + i) * SS * DEPC;
    const int* mrow = mask + (size_t)(b * SS + i) * SS;

    // stage chunk 0 (64 rows x 100 floats = 25.6 KB)
    for (int call = w; call < 25; call += 4)
        __builtin_amdgcn_global_load_lds(
            (const __attribute__((address_space(1))) void*)(src + call * 256 + lane * 4),
            (__attribute__((address_space(3))) void*)(&buf[0][call * 256]),
            16, 0, 0);
    __syncthreads();

    float m_run[3] = {-INFINITY, -INFINITY, -INFINITY};
    float l_run[3] = {0.f, 0.f, 0.f};
    float acc[3] = {0.f, 0.f, 0.f};

    for (int c = 0; c < 4; ++c) {
        // issue next chunk's staging BEFORE compute (latency hides under compute)
        if (c < 3) {
            const float* s2 = src + (c + 1) * 6400;
            for (int call = w; call < 25; call += 4)
                __builtin_amdgcn_global_load_lds(
                    (const __attribute__((address_space(1))) void*)(s2 + call * 256 + lane * 4),
                    (__attribute__((address_space(3))) void*)(&buf[(c + 1) & 1][call * 256]),
                    16, 0, 0);
        }
        // scores for row j = c*64 + lane, heads hbase..hbase+2
        const float4* row4 = (const float4*)(&buf[c & 1][lane * DEPC]);
        float a0 = 0.f, a1 = 0.f, a2 = 0.f;
#pragma unroll
        for (int c4 = 0; c4 < 25; ++c4) {
            float4 e4 = row4[c4];
            const float* ep = (const float*)&e4;
#pragma unroll
            for (int m = 0; m < 4; ++m) {
                int p = 4 * c4 + m;
                a0 += ep[m] * uw[p];
                a1 += ep[m] * uw[DEPC + p];
                a2 += ep[m] * uw[2 * DEPC + p];
            }
        }
        int mk = mrow[c * 64 + lane];
        float s[3];
        s[0] = mk ? fmaxf(a0, 0.f) : -1e6f;
        s[1] = mk ? fmaxf(a1, 0.f) : -1e6f;
        s[2] = mk ? fmaxf(a2, 0.f) : -1e6f;

        // online softmax + PV per head
        const float* vbase = V + (size_t)(b * SS + c * 64) * DD + hbase * 64 + lane;
#pragma unroll
        for (int k = 0; k < 3; ++k) {
            float mc = s[k];
#pragma unroll
            for (int o = 32; o > 0; o >>= 1) mc = fmaxf(mc, __shfl_xor(mc, o, 64));
            float mn = fmaxf(m_run[k], mc);
            float scale = __expf(m_run[k] - mn);
            float p = __expf(s[k] - mn);
            float ps = p;
#pragma unroll
            for (int o = 32; o > 0; o >>= 1) ps += __shfl_xor(ps, o, 64);
            l_run[k] = l_run[k] * scale + ps;
            acc[k] *= scale;
            m_run[k] = mn;
            // PV: acc[k] += sum_jl p(jl) * V[j=c*64+jl][ (hbase+k)*64 + lane ]
            const float* vr = vbase + k * 64;
#pragma unroll
            for (int jl = 0; jl < 64; jl += 4) {
                float p0 = rdlane(p, jl);
                float p1 = rdlane(p, jl + 1);
                float p2 = rdlane(p, jl + 2);
                float p3 = rdlane(p, jl + 3);
                acc[k] += p0 * vr[(size_t)(jl) * DD]
                        + p1 * vr[(size_t)(jl + 1) * DD]
                        + p2 * vr[(size_t)(jl + 2) * DD]
                        + p3 * vr[(size_t)(jl + 3) * DD];
            }
        }
        __syncthreads();  // all waves done with buf[c&1]; next stage may overwrite
    }

#pragma unroll
    for (int k = 0; k < 3; ++k) {
        size_t o = (size_t)(b * SS + i) * DD + (hbase + k) * 64 + lane;
        out[o] = fmaxf(token[o] + acc[k] / l_run[k], 0.f);
    }
}

extern "C" void kernel_launch(void* const* d_in, const int* in_sizes, int n_in,
                              void* d_out, int out_size, void* d_ws, size_t ws_size,
                              hipStream_t stream) {
    const float* token = (const float*)d_in[0];
    const float* edge  = (const float*)d_in[1];
    const int*   mask  = (const int*)d_in[2];
    const float* W_v   = (const float*)d_in[3];
    const float* W_e   = (const float*)d_in[4];
    const float* w_rel = (const float*)d_in[5];
    float* out = (float*)d_out;

    char* ws = (char*)d_ws;
    float* u_t = (float*)(ws);          // 4.8 KB
    float* V   = (float*)(ws + 8192);   // 3.15 MB

    hipLaunchKernelGGL(k_u,     dim3((DEPC * HH + 255) / 256), dim3(256), 0, stream, W_e, w_rel, u_t);
    hipLaunchKernelGGL(k_v,     dim3((BB * SS) / TM, DD / TN), dim3(256), 0, stream, token, W_v, V);
    hipLaunchKernelGGL(k_fused, dim3(SS, BB),                  dim3(256), 0, stream, edge, mask, u_t, V, token, out);
}

// Round 6
// 110.264 us; speedup vs baseline: 1.5037x; 1.5037x over previous
//
#include <hip/hip_runtime.h>
#include <math.h>

#define BB 4
#define SS 256
#define DD 768
#define DEPC 100
#define HH 12

// ---------- K1: u_t[h][p] = sum_d W_e[p][h*64+d] * w_rel[d]  (transposed) ----------
__global__ __launch_bounds__(256) void k_u(const float* __restrict__ W_e,
                                           const float* __restrict__ w_rel,
                                           float* __restrict__ u_t) {
    int e = blockIdx.x * 256 + threadIdx.x;
    if (e >= DEPC * HH) return;
    int p = e / HH, h = e % HH;
    const float4* we = (const float4*)(W_e + p * DD + h * 64);
    const float4* wr = (const float4*)w_rel;
    float acc = 0.f;
#pragma unroll
    for (int c = 0; c < 16; ++c) {
        float4 a = we[c], b = wr[c];
        acc += a.x * b.x + a.y * b.y + a.z * b.z + a.w * b.w;
    }
    u_t[h * DEPC + p] = acc;
}

// ---------- K2: V = token @ W_v, double-buffered (T14 reg-staged) ----------
#define TM 32
#define TN 64
#define TKK 16
__global__ __launch_bounds__(256) void k_v(const float* __restrict__ A,
                                           const float* __restrict__ Bm,
                                           float* __restrict__ C) {
    __shared__ float As[TKK][TM + 4];
    __shared__ float Bs[TKK][TN];
    int t = threadIdx.x;
    int tx = t & 15, ty = t >> 4;
    int kb = t >> 6, cb = t & 63;
    int r0 = blockIdx.x * TM, c0 = blockIdx.y * TN;
    float acc[2][4] = {};

    // stage k0 = 0
    As[tx][ty]      = A[(r0 + ty) * DD + tx];
    As[tx][ty + 16] = A[(r0 + ty + 16) * DD + tx];
#pragma unroll
    for (int q = 0; q < 4; ++q)
        Bs[kb + 4 * q][cb] = Bm[(kb + 4 * q) * DD + c0 + cb];
    __syncthreads();

    for (int k0 = 0; k0 < DD; k0 += TKK) {
        // prefetch next tile into registers while computing current
        float an0 = 0.f, an1 = 0.f, bn[4] = {};
        if (k0 + TKK < DD) {
            int kn = k0 + TKK;
            an0 = A[(r0 + ty) * DD + kn + tx];
            an1 = A[(r0 + ty + 16) * DD + kn + tx];
#pragma unroll
            for (int q = 0; q < 4; ++q)
                bn[q] = Bm[(kn + kb + 4 * q) * DD + c0 + cb];
        }
#pragma unroll
        for (int kk = 0; kk < TKK; ++kk) {
            float a0 = As[kk][2 * ty], a1 = As[kk][2 * ty + 1];
            float4 b = *(const float4*)&Bs[kk][4 * tx];
            acc[0][0] += a0 * b.x; acc[0][1] += a0 * b.y;
            acc[0][2] += a0 * b.z; acc[0][3] += a0 * b.w;
            acc[1][0] += a1 * b.x; acc[1][1] += a1 * b.y;
            acc[1][2] += a1 * b.z; acc[1][3] += a1 * b.w;
        }
        __syncthreads();
        if (k0 + TKK < DD) {
            As[tx][ty]      = an0;
            As[tx][ty + 16] = an1;
#pragma unroll
            for (int q = 0; q < 4; ++q) Bs[kb + 4 * q][cb] = bn[q];
        }
        __syncthreads();
    }
#pragma unroll
    for (int m = 0; m < 2; ++m) {
        float4 v = make_float4(acc[m][0], acc[m][1], acc[m][2], acc[m][3]);
        *(float4*)&C[(size_t)(r0 + 2 * ty + m) * DD + c0 + 4 * tx] = v;
    }
}

// ---------- K3: scores = mask ? relu(E . u) : -1e6 ----------
// Block = 64-row j-chunk. Edge staged via global_load_lds (linear LDS, stride-100
// self-staggered = conflict-free). u fetched in 5 register phases (<=15 float4 live),
// component-wise partial accumulators break the FMA dependence chain.
__global__ __launch_bounds__(256) void k_sc(const float* __restrict__ edge,
                                            const int* __restrict__ mask,
                                            const float* __restrict__ ut,
                                            float* __restrict__ scores) {
    __shared__ float buf[64 * DEPC];  // 25.6 KB
    int t = threadIdx.x;
    int jc = blockIdx.x & 3;
    int i  = blockIdx.x >> 2;
    int b  = blockIdx.y;
    int lane = t & 63, w = t >> 6;

    const float* src = edge + (size_t)((b * SS + i) * SS + jc * 64) * DEPC;
    for (int call = w; call < 25; call += 4)
        __builtin_amdgcn_global_load_lds(
            (const __attribute__((address_space(1))) void*)(src + call * 256 + lane * 4),
            (__attribute__((address_space(3))) void*)(buf + call * 256),
            16, 0, 0);

    int hbase = __builtin_amdgcn_readfirstlane(w * 3);  // 3 heads per wave
    const float* uw = ut + hbase * DEPC;
    __syncthreads();

    const float4* row4 = (const float4*)(buf + lane * DEPC);
    float4 A0 = {0, 0, 0, 0}, A1 = {0, 0, 0, 0}, A2 = {0, 0, 0, 0};

#pragma unroll
    for (int ph = 0; ph < 5; ++ph) {
        float4 e4[5], u0[5], u1[5], u2[5];
#pragma unroll
        for (int q = 0; q < 5; ++q) {
            int p4 = ph * 5 + q;
            e4[q] = row4[p4];
            u0[q] = *(const float4*)(uw + 4 * p4);
            u1[q] = *(const float4*)(uw + DEPC + 4 * p4);
            u2[q] = *(const float4*)(uw + 2 * DEPC + 4 * p4);
        }
#pragma unroll
        for (int q = 0; q < 5; ++q) {
            A0.x += e4[q].x * u0[q].x; A0.y += e4[q].y * u0[q].y;
            A0.z += e4[q].z * u0[q].z; A0.w += e4[q].w * u0[q].w;
            A1.x += e4[q].x * u1[q].x; A1.y += e4[q].y * u1[q].y;
            A1.z += e4[q].z * u1[q].z; A1.w += e4[q].w * u1[q].w;
            A2.x += e4[q].x * u2[q].x; A2.y += e4[q].y * u2[q].y;
            A2.z += e4[q].z * u2[q].z; A2.w += e4[q].w * u2[q].w;
        }
    }
    float a0 = (A0.x + A0.y) + (A0.z + A0.w);
    float a1 = (A1.x + A1.y) + (A1.z + A1.w);
    float a2 = (A2.x + A2.y) + (A2.z + A2.w);

    int j = jc * 64 + lane;
    int mk = mask[(size_t)(b * SS + i) * SS + j];
    size_t sb = (((size_t)b * HH + hbase) * SS + i) * SS + j;
    scores[sb]                       = mk ? fmaxf(a0, 0.f) : -1e6f;
    scores[sb + (size_t)SS * SS]     = mk ? fmaxf(a1, 0.f) : -1e6f;
    scores[sb + 2 * (size_t)SS * SS] = mk ? fmaxf(a2, 0.f) : -1e6f;
}

// ---------- K4: softmax over j + ctx = P@V + relu(token+ctx) ----------
#define GG 4
__global__ __launch_bounds__(256) void k_ctx(const float* __restrict__ scores,
                                             const float* __restrict__ V,
                                             const float* __restrict__ token,
                                             float* __restrict__ out) {
    __shared__ float sc[GG][HH][SS];  // 48 KB
    int t = threadIdx.x, b = blockIdx.y, i0 = blockIdx.x * GG;
    for (int idx = t; idx < GG * HH * (SS / 4); idx += 256) {
        int jc = idx & 63, rr = idx >> 6;
        int g = rr / HH, h = rr % HH;
        float4 v = *(const float4*)(scores + (((size_t)b * HH + h) * SS + (i0 + g)) * SS + 4 * jc);
        *(float4*)&sc[g][h][4 * jc] = v;
    }
    __syncthreads();
    int lane = t & 63, w = t >> 6;
    for (int rr = w; rr < GG * HH; rr += 4) {
        int g = rr / HH, h = rr % HH;
        float x0 = sc[g][h][lane],       x1 = sc[g][h][lane + 64];
        float x2 = sc[g][h][lane + 128], x3 = sc[g][h][lane + 192];
        float m = fmaxf(fmaxf(x0, x1), fmaxf(x2, x3));
#pragma unroll
        for (int o = 32; o > 0; o >>= 1) m = fmaxf(m, __shfl_xor(m, o, 64));
        x0 = __expf(x0 - m); x1 = __expf(x1 - m);
        x2 = __expf(x2 - m); x3 = __expf(x3 - m);
        float s = x0 + x1 + x2 + x3;
#pragma unroll
        for (int o = 32; o > 0; o >>= 1) s += __shfl_xor(s, o, 64);
        float inv = 1.0f / s;
        sc[g][h][lane] = x0 * inv;       sc[g][h][lane + 64] = x1 * inv;
        sc[g][h][lane + 128] = x2 * inv; sc[g][h][lane + 192] = x3 * inv;
    }
    __syncthreads();
    float acc[3][GG] = {};
    for (int j0 = 0; j0 < SS; j0 += 4) {
#pragma unroll
        for (int a = 0; a < 3; ++a) {
            int hd = t + 256 * a;
            int h = hd >> 6;
            float v0 = V[(size_t)(b * SS + j0) * DD + hd];
            float v1 = V[(size_t)(b * SS + j0 + 1) * DD + hd];
            float v2 = V[(size_t)(b * SS + j0 + 2) * DD + hd];
            float v3 = V[(size_t)(b * SS + j0 + 3) * DD + hd];
#pragma unroll
            for (int g = 0; g < GG; ++g) {
                float4 p = *(const float4*)&sc[g][h][j0];
                acc[a][g] += p.x * v0 + p.y * v1 + p.z * v2 + p.w * v3;
            }
        }
    }
#pragma unroll
    for (int a = 0; a < 3; ++a) {
        int hd = t + 256 * a;
#pragma unroll
        for (int g = 0; g < GG; ++g) {
            size_t o = (size_t)(b * SS + i0 + g) * DD + hd;
            out[o] = fmaxf(token[o] + acc[a][g], 0.f);
        }
    }
}

extern "C" void kernel_launch(void* const* d_in, const int* in_sizes, int n_in,
                              void* d_out, int out_size, void* d_ws, size_t ws_size,
                              hipStream_t stream) {
    const float* token = (const float*)d_in[0];
    const float* edge  = (const float*)d_in[1];
    const int*   mask  = (const int*)d_in[2];
    const float* W_v   = (const float*)d_in[3];
    const float* W_e   = (const float*)d_in[4];
    const float* w_rel = (const float*)d_in[5];
    float* out = (float*)d_out;

    char* ws = (char*)d_ws;
    float* u_t    = (float*)(ws);                                   // 4.8 KB
    float* V      = (float*)(ws + 8192);                            // 3.15 MB
    float* scores = (float*)(ws + 8192 + (size_t)BB * SS * DD * 4); // 12.6 MB

    hipLaunchKernelGGL(k_u,   dim3((DEPC * HH + 255) / 256), dim3(256), 0, stream, W_e, w_rel, u_t);
    hipLaunchKernelGGL(k_v,   dim3((BB * SS) / TM, DD / TN), dim3(256), 0, stream, token, W_v, V);
    hipLaunchKernelGGL(k_sc,  dim3(SS * 4, BB),              dim3(256), 0, stream, edge, mask, u_t, scores);
    hipLaunchKernelGGL(k_ctx, dim3(SS / GG, BB),             dim3(256), 0, stream, scores, V, token, out);
}

// Round 7
// 94.990 us; speedup vs baseline: 1.7454x; 1.1608x over previous
//
#include <hip/hip_runtime.h>
#include <math.h>

#define BB 4
#define SS 256
#define DD 768
#define DEPC 100
#define HH 12

// ---------- K1: u_t[h][p] = sum_d W_e[p][h*64+d] * w_rel[d]  (transposed) ----------
__global__ __launch_bounds__(256) void k_u(const float* __restrict__ W_e,
                                           const float* __restrict__ w_rel,
                                           float* __restrict__ u_t) {
    int e = blockIdx.x * 256 + threadIdx.x;
    if (e >= DEPC * HH) return;
    int p = e / HH, h = e % HH;
    const float4* we = (const float4*)(W_e + p * DD + h * 64);
    const float4* wr = (const float4*)w_rel;
    float acc = 0.f;
#pragma unroll
    for (int c = 0; c < 16; ++c) {
        float4 a = we[c], b = wr[c];
        acc += a.x * b.x + a.y * b.y + a.z * b.z + a.w * b.w;
    }
    u_t[h * DEPC + p] = acc;
}

// ---------- K2: V = token @ W_v, double-buffered (unchanged from R6) ----------
#define TM 32
#define TN 64
#define TKK 16
__global__ __launch_bounds__(256) void k_v(const float* __restrict__ A,
                                           const float* __restrict__ Bm,
                                           float* __restrict__ C) {
    __shared__ float As[TKK][TM + 4];
    __shared__ float Bs[TKK][TN];
    int t = threadIdx.x;
    int tx = t & 15, ty = t >> 4;
    int kb = t >> 6, cb = t & 63;
    int r0 = blockIdx.x * TM, c0 = blockIdx.y * TN;
    float acc[2][4] = {};

    As[tx][ty]      = A[(r0 + ty) * DD + tx];
    As[tx][ty + 16] = A[(r0 + ty + 16) * DD + tx];
#pragma unroll
    for (int q = 0; q < 4; ++q)
        Bs[kb + 4 * q][cb] = Bm[(kb + 4 * q) * DD + c0 + cb];
    __syncthreads();

    for (int k0 = 0; k0 < DD; k0 += TKK) {
        float an0 = 0.f, an1 = 0.f, bn[4] = {};
        if (k0 + TKK < DD) {
            int kn = k0 + TKK;
            an0 = A[(r0 + ty) * DD + kn + tx];
            an1 = A[(r0 + ty + 16) * DD + kn + tx];
#pragma unroll
            for (int q = 0; q < 4; ++q)
                bn[q] = Bm[(kn + kb + 4 * q) * DD + c0 + cb];
        }
#pragma unroll
        for (int kk = 0; kk < TKK; ++kk) {
            float a0 = As[kk][2 * ty], a1 = As[kk][2 * ty + 1];
            float4 b = *(const float4*)&Bs[kk][4 * tx];
            acc[0][0] += a0 * b.x; acc[0][1] += a0 * b.y;
            acc[0][2] += a0 * b.z; acc[0][3] += a0 * b.w;
            acc[1][0] += a1 * b.x; acc[1][1] += a1 * b.y;
            acc[1][2] += a1 * b.z; acc[1][3] += a1 * b.w;
        }
        __syncthreads();
        if (k0 + TKK < DD) {
            As[tx][ty]      = an0;
            As[tx][ty + 16] = an1;
#pragma unroll
            for (int q = 0; q < 4; ++q) Bs[kb + 4 * q][cb] = bn[q];
        }
        __syncthreads();
    }
#pragma unroll
    for (int m = 0; m < 2; ++m) {
        float4 v = make_float4(acc[m][0], acc[m][1], acc[m][2], acc[m][3]);
        *(float4*)&C[(size_t)(r0 + 2 * ty + m) * DD + c0 + 4 * tx] = v;
    }
}

// ---------- K3: scores, intra-block double-buffered streaming ----------
// Block = (i,b). 4 chunks x 64 rows. Next chunk's global_load_lds issued BEFORE
// computing current chunk -> HBM busy through the vmcnt drain at the barrier.
__global__ __launch_bounds__(256) void k_sc(const float* __restrict__ edge,
                                            const int* __restrict__ mask,
                                            const float* __restrict__ ut,
                                            float* __restrict__ scores) {
    __shared__ float buf[2][64 * DEPC];  // 51.2 KB
    int t = threadIdx.x;
    int i = blockIdx.x, b = blockIdx.y;
    int lane = t & 63, w = t >> 6;
    const float* src = edge + (size_t)(b * SS + i) * SS * DEPC;
    const int* mrow = mask + (size_t)(b * SS + i) * SS;

    for (int call = w; call < 25; call += 4)
        __builtin_amdgcn_global_load_lds(
            (const __attribute__((address_space(1))) void*)(src + call * 256 + lane * 4),
            (__attribute__((address_space(3))) void*)(&buf[0][call * 256]),
            16, 0, 0);

    int hbase = __builtin_amdgcn_readfirstlane(w * 3);
    const float* uw = ut + hbase * DEPC;
    __syncthreads();

    for (int c = 0; c < 4; ++c) {
        if (c < 3) {
            const float* s2 = src + (c + 1) * 6400;
            for (int call = w; call < 25; call += 4)
                __builtin_amdgcn_global_load_lds(
                    (const __attribute__((address_space(1))) void*)(s2 + call * 256 + lane * 4),
                    (__attribute__((address_space(3))) void*)(&buf[(c + 1) & 1][call * 256]),
                    16, 0, 0);
        }
        const float4* row4 = (const float4*)(&buf[c & 1][lane * DEPC]);
        float4 A0 = {0, 0, 0, 0}, A1 = {0, 0, 0, 0}, A2 = {0, 0, 0, 0};
#pragma unroll
        for (int ph = 0; ph < 5; ++ph) {
            float4 e4[5], u0[5], u1[5], u2[5];
#pragma unroll
            for (int q = 0; q < 5; ++q) {
                int p4 = ph * 5 + q;
                e4[q] = row4[p4];
                u0[q] = *(const float4*)(uw + 4 * p4);
                u1[q] = *(const float4*)(uw + DEPC + 4 * p4);
                u2[q] = *(const float4*)(uw + 2 * DEPC + 4 * p4);
            }
#pragma unroll
            for (int q = 0; q < 5; ++q) {
                A0.x += e4[q].x * u0[q].x; A0.y += e4[q].y * u0[q].y;
                A0.z += e4[q].z * u0[q].z; A0.w += e4[q].w * u0[q].w;
                A1.x += e4[q].x * u1[q].x; A1.y += e4[q].y * u1[q].y;
                A1.z += e4[q].z * u1[q].z; A1.w += e4[q].w * u1[q].w;
                A2.x += e4[q].x * u2[q].x; A2.y += e4[q].y * u2[q].y;
                A2.z += e4[q].z * u2[q].z; A2.w += e4[q].w * u2[q].w;
            }
        }
        float a0 = (A0.x + A0.y) + (A0.z + A0.w);
        float a1 = (A1.x + A1.y) + (A1.z + A1.w);
        float a2 = (A2.x + A2.y) + (A2.z + A2.w);

        int j = c * 64 + lane;
        int mk = mrow[j];
        size_t sb = (((size_t)b * HH + hbase) * SS + i) * SS + j;
        scores[sb]                       = mk ? fmaxf(a0, 0.f) : -1e6f;
        scores[sb + (size_t)SS * SS]     = mk ? fmaxf(a1, 0.f) : -1e6f;
        scores[sb + 2 * (size_t)SS * SS] = mk ? fmaxf(a2, 0.f) : -1e6f;
        __syncthreads();  // waves done with buf[c&1]; drains next chunk's loads
    }
}

// ---------- K4: softmax + ctx, 512 threads (j-range split across halves) ----------
#define GG 4
__global__ __launch_bounds__(512) void k_ctx(const float* __restrict__ scores,
                                             const float* __restrict__ V,
                                             const float* __restrict__ token,
                                             float* __restrict__ out) {
    __shared__ float sc[GG][HH][SS];  // 48 KB
    __shared__ float red[GG][DD];     // 12.3 KB partials
    int t = threadIdx.x, b = blockIdx.y, i0 = blockIdx.x * GG;
    for (int idx = t; idx < GG * HH * (SS / 4); idx += 512) {
        int jc = idx & 63, rr = idx >> 6;
        int g = rr / HH, h = rr % HH;
        float4 v = *(const float4*)(scores + (((size_t)b * HH + h) * SS + (i0 + g)) * SS + 4 * jc);
        *(float4*)&sc[g][h][4 * jc] = v;
    }
    __syncthreads();
    int lane = t & 63, w = t >> 6;  // 8 waves
    for (int rr = w; rr < GG * HH; rr += 8) {
        int g = rr / HH, h = rr % HH;
        float x0 = sc[g][h][lane],       x1 = sc[g][h][lane + 64];
        float x2 = sc[g][h][lane + 128], x3 = sc[g][h][lane + 192];
        float m = fmaxf(fmaxf(x0, x1), fmaxf(x2, x3));
#pragma unroll
        for (int o = 32; o > 0; o >>= 1) m = fmaxf(m, __shfl_xor(m, o, 64));
        x0 = __expf(x0 - m); x1 = __expf(x1 - m);
        x2 = __expf(x2 - m); x3 = __expf(x3 - m);
        float s = x0 + x1 + x2 + x3;
#pragma unroll
        for (int o = 32; o > 0; o >>= 1) s += __shfl_xor(s, o, 64);
        float inv = 1.0f / s;
        sc[g][h][lane] = x0 * inv;       sc[g][h][lane + 64] = x1 * inv;
        sc[g][h][lane + 128] = x2 * inv; sc[g][h][lane + 192] = x3 * inv;
    }
    __syncthreads();
    // PV: halves split the j-range; tt indexes the 768 output dims (3 per thread)
    int half = t >> 8, tt = t & 255;
    float acc[3][GG] = {};
    for (int j0 = half * 128; j0 < half * 128 + 128; j0 += 4) {
#pragma unroll
        for (int a = 0; a < 3; ++a) {
            int hd = tt + 256 * a;
            int h = hd >> 6;
            float v0 = V[(size_t)(b * SS + j0) * DD + hd];
            float v1 = V[(size_t)(b * SS + j0 + 1) * DD + hd];
            float v2 = V[(size_t)(b * SS + j0 + 2) * DD + hd];
            float v3 = V[(size_t)(b * SS + j0 + 3) * DD + hd];
#pragma unroll
            for (int g = 0; g < GG; ++g) {
                float4 p = *(const float4*)&sc[g][h][j0];
                acc[a][g] += p.x * v0 + p.y * v1 + p.z * v2 + p.w * v3;
            }
        }
    }
    if (half == 1) {
#pragma unroll
        for (int a = 0; a < 3; ++a)
#pragma unroll
            for (int g = 0; g < GG; ++g) red[g][tt + 256 * a] = acc[a][g];
    }
    __syncthreads();
    if (half == 0) {
#pragma unroll
        for (int a = 0; a < 3; ++a) {
            int hd = tt + 256 * a;
#pragma unroll
            for (int g = 0; g < GG; ++g) {
                size_t o = (size_t)(b * SS + i0 + g) * DD + hd;
                out[o] = fmaxf(token[o] + acc[a][g] + red[g][hd], 0.f);
            }
        }
    }
}

extern "C" void kernel_launch(void* const* d_in, const int* in_sizes, int n_in,
                              void* d_out, int out_size, void* d_ws, size_t ws_size,
                              hipStream_t stream) {
    const float* token = (const float*)d_in[0];
    const float* edge  = (const float*)d_in[1];
    const int*   mask  = (const int*)d_in[2];
    const float* W_v   = (const float*)d_in[3];
    const float* W_e   = (const float*)d_in[4];
    const float* w_rel = (const float*)d_in[5];
    float* out = (float*)d_out;

    char* ws = (char*)d_ws;
    float* u_t    = (float*)(ws);                                   // 4.8 KB
    float* V      = (float*)(ws + 8192);                            // 3.15 MB
    float* scores = (float*)(ws + 8192 + (size_t)BB * SS * DD * 4); // 12.6 MB

    hipLaunchKernelGGL(k_u,   dim3((DEPC * HH + 255) / 256), dim3(256), 0, stream, W_e, w_rel, u_t);
    hipLaunchKernelGGL(k_v,   dim3((BB * SS) / TM, DD / TN), dim3(256), 0, stream, token, W_v, V);
    hipLaunchKernelGGL(k_sc,  dim3(SS, BB),                  dim3(256), 0, stream, edge, mask, u_t, scores);
    hipLaunchKernelGGL(k_ctx, dim3(SS / GG, BB),             dim3(512), 0, stream, scores, V, token, out);
}